// Round 27
// baseline (6392.808 us; speedup 1.0000x reference)
//
#include <hip/hip_runtime.h>
#include <cstdint>

#pragma clang fp contract(off)

typedef unsigned char u8;

// r23 = 3.40ms best. Analysis: GEMM is LDS-pipe-bound (256/288 ds_reads per
// slice are WEIGHT reads, broadcast 16B/instr). r27: weights bypass LDS via
// wave-uniform (readfirstlane) SGPR-based loads -> s_load through scalar
// cache; LDS carries spikes only (36.9KB, 4 blocks/CU). BIT-EXACT: same
// ascending-c fma order within 256-chunks, seq chunk folds, r20 epilogue/LIF.

__device__ __forceinline__ void lif_step(float& mem, float& spk, float v) {
    float m1 = __fmul_rn(mem, 0.25f);            // exact (pow2)
    float m2 = __fmul_rn(m1, (1.0f - spk));      // exact (x0 or x1)
    mem = __fadd_rn(m2, v);                      // one rounding
    spk = (mem > 0.5f) ? 1.0f : 0.0f;
}

__device__ __forceinline__ float ubf(uint32_t x, int j) {
    return (float)((x >> (j * 8)) & 0xffu);      // v_cvt_f32_ubyteN
}

// ---- LIF over T=4 from f32 source (+ optional pos broadcast) -> u8 ----
__global__ __launch_bounds__(256) void lif_f(const float* __restrict__ src,
                                             const float* __restrict__ pos,
                                             u8* __restrict__ dst,
                                             size_t plane, size_t cn) {
    size_t i = (size_t)blockIdx.x * 256 + threadIdx.x;
    if (i >= plane) return;
    float p = pos ? pos[i % cn] : 0.0f;
    float mem = 0.0f, spk = 0.0f;
#pragma unroll
    for (int t = 0; t < 4; ++t) {
        float v = src[(size_t)t * plane + i];
        if (pos) v = __fadd_rn(v, p);
        lif_step(mem, spk, v);
        dst[(size_t)t * plane + i] = (u8)spk;
    }
}

// ---- u8 transpose [g][R][576] -> [g][576][R], 32x32 LDS tiles ----
__global__ __launch_bounds__(256) void transp(const u8* __restrict__ in,
                                              u8* __restrict__ out, int R) {
    __shared__ u8 tile[32][33];
    int g = blockIdx.z;
    int r0 = blockIdx.y * 32;
    int n0 = blockIdx.x * 32;
    int tx = threadIdx.x & 31, ty = threadIdx.x >> 5;  // ty 0..7
    const u8* ip = in + ((size_t)g * R + r0) * 576 + n0;
#pragma unroll
    for (int k = 0; k < 4; ++k) {
        int r = ty + k * 8;
        tile[r][tx] = ip[(size_t)r * 576 + tx];
    }
    __syncthreads();
    u8* op = out + ((size_t)g * 576 + n0) * R + r0;
#pragma unroll
    for (int k = 0; k < 4; ++k) {
        int r = ty + k * 8;
        op[(size_t)r * R + tx] = tile[tx][r];
    }
}

// ===========================================================================
// Tiled 1x1-conv: block = 64n x 32o, b fixed. LDS-staged 128-c spike slices;
// weights read via wave-uniform SGPR bases (scalar cache, no LDS).
// p[8][4] in-chunk accs (ascending c), a[8][4] folded at 256-c boundaries.
// DO_LIF=1: BN+LIF -> u8 dst.  DO_LIF=0: BN+residual -> f32 outp.
// ===========================================================================
template <int DO_LIF>
__global__ __launch_bounds__(256) void pw_tile(
    const float* __restrict__ W, const u8* __restrict__ ST,
    const float* __restrict__ sc, const float* __restrict__ bi,
    const float* __restrict__ cb, const float* __restrict__ res,
    u8* __restrict__ dst, float* __restrict__ outp, int O, int C) {
    __shared__ u8 spk[4][64][144];
    int lane = threadIdx.x & 63;
    int wave = __builtin_amdgcn_readfirstlane(threadIdx.x >> 6);  // SGPR
    int n0 = blockIdx.x * 64;
    int o0 = blockIdx.y * 32;
    int b = blockIdx.z;
    int n = n0 + lane;
    int wo = wave * 8;

    // wave-uniform weight row bases (SGPR) -> s_load path
    const float* wr0 = W + (size_t)(o0 + wo + 0) * C;
    const float* wr1 = W + (size_t)(o0 + wo + 1) * C;
    const float* wr2 = W + (size_t)(o0 + wo + 2) * C;
    const float* wr3 = W + (size_t)(o0 + wo + 3) * C;
    const float* wr4 = W + (size_t)(o0 + wo + 4) * C;
    const float* wr5 = W + (size_t)(o0 + wo + 5) * C;
    const float* wr6 = W + (size_t)(o0 + wo + 6) * C;
    const float* wr7 = W + (size_t)(o0 + wo + 7) * C;

    float a[8][4] = {}, p[8][4] = {};
    for (int c0 = 0; c0 < C; c0 += 256) {
        for (int s = 0; s < 2; ++s) {
            int cs = c0 + s * 128;
            __syncthreads();
            {   // stage spikes: 256 rows (4t x 64n), 128B each
                int t = threadIdx.x >> 6, nl = threadIdx.x & 63;
                const uint4* g4 = (const uint4*)(ST +
                    ((size_t)(t * 8 + b) * 576 + n0 + nl) * C + cs);
                uint4* l4 = (uint4*)&spk[t][nl][0];
#pragma unroll
                for (int q = 0; q < 8; ++q) l4[q] = g4[q];
            }
            __syncthreads();
            for (int cq = 0; cq < 128; cq += 16) {
                uint4 s0 = *(const uint4*)&spk[0][lane][cq];
                uint4 s1 = *(const uint4*)&spk[1][lane][cq];
                uint4 s2 = *(const uint4*)&spk[2][lane][cq];
                uint4 s3 = *(const uint4*)&spk[3][lane][cq];
#pragma unroll
                for (int d = 0; d < 4; ++d) {
                    int co = cs + cq + d * 4;
                    float4 wk[8];
                    wk[0] = *(const float4*)(wr0 + co);
                    wk[1] = *(const float4*)(wr1 + co);
                    wk[2] = *(const float4*)(wr2 + co);
                    wk[3] = *(const float4*)(wr3 + co);
                    wk[4] = *(const float4*)(wr4 + co);
                    wk[5] = *(const float4*)(wr5 + co);
                    wk[6] = *(const float4*)(wr6 + co);
                    wk[7] = *(const float4*)(wr7 + co);
                    uint32_t u0 = (&s0.x)[d], u1 = (&s1.x)[d];
                    uint32_t u2 = (&s2.x)[d], u3 = (&s3.x)[d];
#pragma unroll
                    for (int j = 0; j < 4; ++j) {
                        float f0 = ubf(u0, j), f1 = ubf(u1, j);
                        float f2 = ubf(u2, j), f3 = ubf(u3, j);
#pragma unroll
                        for (int k = 0; k < 8; ++k) {
                            float w = (&wk[k].x)[j];
                            p[k][0] = __fmaf_rn(f0, w, p[k][0]);
                            p[k][1] = __fmaf_rn(f1, w, p[k][1]);
                            p[k][2] = __fmaf_rn(f2, w, p[k][2]);
                            p[k][3] = __fmaf_rn(f3, w, p[k][3]);
                        }
                    }
                }
            }
        }
#pragma unroll
        for (int k = 0; k < 8; ++k)
#pragma unroll
            for (int t = 0; t < 4; ++t) {
                a[k][t] = __fadd_rn(a[k][t], p[k][t]);
                p[k][t] = 0.0f;
            }
    }
    size_t planeO = (size_t)8 * O * 576;
#pragma unroll
    for (int k = 0; k < 8; ++k) {
        int o = o0 + wo + k;
        float s_ = sc[o], b_ = bi[o];
        if (DO_LIF) {
            float mem = 0.f, spkr = 0.f;
#pragma unroll
            for (int t = 0; t < 4; ++t) {
                float acc = a[k][t];
                if (cb) acc = __fadd_rn(acc, cb[o]);
                float v = __fadd_rn(__fmul_rn(acc, s_), b_);
                lif_step(mem, spkr, v);
                dst[(size_t)t * planeO + ((size_t)b * O + o) * 576 + n] = (u8)spkr;
            }
        } else {
#pragma unroll
            for (int t = 0; t < 4; ++t) {
                float acc = a[k][t];
                if (cb) acc = __fadd_rn(acc, cb[o]);
                float v = __fadd_rn(__fmul_rn(acc, s_), b_);
                size_t idx = (size_t)t * planeO + ((size_t)b * O + o) * 576 + n;
                outp[idx] = __fadd_rn(res[idx], v);
            }
        }
    }
}

// ---- fused depthwise 3x3 (cross-correlation, SAME, zero-pad) + BN + LIF ----
__global__ __launch_bounds__(256) void dwlif(
    const u8* __restrict__ in, const float* __restrict__ w9,
    const float* __restrict__ sc, const float* __restrict__ bi,
    u8* __restrict__ dst, int Ch) {
    size_t i = (size_t)blockIdx.x * 256 + threadIdx.x;
    size_t total = (size_t)8 * Ch * 576;
    if (i >= total) return;
    int n = (int)(i % 576);
    int c = (int)((i / 576) % Ch);
    int b = (int)(i / ((size_t)Ch * 576));
    int h = n / 24, w = n % 24;
    const float* wc = w9 + (size_t)c * 9;
    float s_ = sc[c], b_ = bi[c];
    float mem = 0.0f, spk = 0.0f;
#pragma unroll
    for (int t = 0; t < 4; ++t) {
        const u8* base = in + ((size_t)(t * 8 + b) * Ch + c) * 576;
        float acc = 0.0f;
#pragma unroll
        for (int ii = 0; ii < 3; ++ii) {
            int hh = h + ii - 1;
            if (hh < 0 || hh >= 24) continue;
#pragma unroll
            for (int jj = 0; jj < 3; ++jj) {
                int ww = w + jj - 1;
                if (ww < 0 || ww >= 24) continue;
                if (base[hh * 24 + ww]) acc = __fadd_rn(acc, wc[ii * 3 + jj]);
            }
        }
        float v = __fadd_rn(__fmul_rn(acc, s_), b_);
        lif_step(mem, spk, v);
        dst[((size_t)(t * 8 + b) * Ch + c) * 576 + n] = (u8)spk;
    }
}

// ---- bitpack spikes along n: [rows][576] u8 -> [rows][18] u32 ----
__global__ __launch_bounds__(256) void bitpack(const u8* __restrict__ in,
                                               uint32_t* __restrict__ out,
                                               size_t nwords) {
    size_t i = (size_t)blockIdx.x * 256 + threadIdx.x;
    if (i >= nwords) return;
    size_t r = i / 18; int w = (int)(i % 18);
    const u8* p = in + r * 576 + (size_t)w * 32;
    uint32_t m = 0;
#pragma unroll
    for (int j = 0; j < 32; ++j) m |= (p[j] ? 1u : 0u) << j;
    out[i] = m;
}

// ---- kv via AND+popcount (exact integer, order-free) ----
__global__ __launch_bounds__(256) void kvk_bit(const uint32_t* __restrict__ KP,
                                               const uint32_t* __restrict__ VP,
                                               float* __restrict__ KV) {
    int e = threadIdx.x;       // 0..255
    int h = blockIdx.x;        // 0..7
    int g = blockIdx.y;        // 0..31
    uint32_t v[18];
    const uint32_t* vp = VP + ((size_t)g * 2048 + h * 256 + e) * 18;
#pragma unroll
    for (int w = 0; w < 18; ++w) v[w] = vp[w];
    __shared__ uint32_t ks[64][18];
    const uint32_t* kp = KP + ((size_t)g * 512 + h * 64) * 18;
    for (int idx = threadIdx.x; idx < 64 * 18; idx += 256)
        ks[idx / 18][idx % 18] = kp[idx];
    __syncthreads();
    float* kvo = KV + ((size_t)(g * 8 + h)) * (64 * 256);
    for (int d = 0; d < 64; ++d) {
        int s = 0;
#pragma unroll
        for (int w = 0; w < 18; ++w) s += __popc(ks[d][w] & v[w]);
        kvo[d * 256 + e] = (float)s;  // exact int
    }
}

// ---- o = 0.25 * q.kv (exact ints) + LIF -> u8 std; q transposed ----
__global__ __launch_bounds__(64) void olifT(const u8* __restrict__ QT,
                                            const float* __restrict__ KV,
                                            u8* __restrict__ dst) {
    int n = blockIdx.x * 64 + threadIdx.x;
    int ef = blockIdx.y;
    int b = blockIdx.z;
    int h = ef >> 8, e = ef & 255;
    float mem = 0.f, spk = 0.f;
#pragma unroll
    for (int t = 0; t < 4; ++t) {
        int g = t * 8 + b;
        const u8* q = QT + ((size_t)g * 576 + n) * 512 + h * 64;
        const float* kvg = KV + ((size_t)(g * 8 + h)) * (64 * 256) + e;
        float acc = 0.f;
#pragma unroll
        for (int dq = 0; dq < 64; dq += 16) {
            uint4 qw = *(const uint4*)(q + dq);
#pragma unroll
            for (int d = 0; d < 4; ++d) {
                uint32_t u = (&qw.x)[d];
#pragma unroll
                for (int j = 0; j < 4; ++j)
                    acc = __fmaf_rn(ubf(u, j), kvg[(size_t)(dq + d * 4 + j) * 256], acc);
            }
        }
        float v = __fmul_rn(0.25f, acc);  // exact
        lif_step(mem, spk, v);
        dst[((size_t)g * 2048 + ef) * 576 + n] = (u8)spk;
    }
}

// ---------------------------------------------------------------------------
extern "C" void kernel_launch(void* const* d_in, const int* in_sizes, int n_in,
                              void* d_out, int out_size, void* d_ws, size_t ws_size,
                              hipStream_t stream) {
    const float* x        = (const float*)d_in[0];
    const float* pw1_w    = (const float*)d_in[1];
    const float* pw1_s    = (const float*)d_in[2];
    const float* pw1_b    = (const float*)d_in[3];
    const float* dw_w     = (const float*)d_in[4];
    const float* dw_s     = (const float*)d_in[5];
    const float* dw_b     = (const float*)d_in[6];
    const float* pw2_w    = (const float*)d_in[7];
    const float* pw2_s    = (const float*)d_in[8];
    const float* pw2_b    = (const float*)d_in[9];
    const float* s_pos    = (const float*)d_in[10];
    const float* q_w      = (const float*)d_in[11];
    const float* q_s      = (const float*)d_in[12];
    const float* q_b      = (const float*)d_in[13];
    const float* k_w      = (const float*)d_in[14];
    const float* k_s      = (const float*)d_in[15];
    const float* k_b      = (const float*)d_in[16];
    const float* v_w      = (const float*)d_in[17];
    const float* v_s      = (const float*)d_in[18];
    const float* v_b      = (const float*)d_in[19];
    const float* proj_w   = (const float*)d_in[20];
    const float* proj_s   = (const float*)d_in[21];
    const float* proj_b   = (const float*)d_in[22];
    const float* fc1_w    = (const float*)d_in[23];
    const float* fc1_c    = (const float*)d_in[24];
    const float* fc1_s    = (const float*)d_in[25];
    const float* fc1_b    = (const float*)d_in[26];
    const float* fc2_w    = (const float*)d_in[27];
    const float* fc2_c    = (const float*)d_in[28];
    const float* fc2_s    = (const float*)d_in[29];
    const float* fc2_b    = (const float*)d_in[30];
    float* out = (float*)d_out;
    (void)ws_size; (void)n_in; (void)in_sizes; (void)out_size;

    const size_t MB = 1024 * 1024;
    char* Wp = (char*)d_ws;
    float*    X2  = (float*)(Wp);             // [0,40MB)    x2 -> x3 f32
    float*    KV  = (float*)(Wp + 40 * MB);   // [40,60MB)
    u8*       A   = (u8*)(Wp + 60 * MB);      // [60,70MB)   S1B std
    u8*       AT  = (u8*)(Wp + 70 * MB);      // [70,80MB)   S1B transposed
    u8*       B   = (u8*)(Wp + 80 * MB);      // [80,100MB)  2S1B std (y1)
    u8*       BT  = (u8*)(Wp + 100 * MB);     // [100,120MB) 2S1B T (y2_T)
    u8*       C4  = (u8*)(Wp + 120 * MB);     // [120,158MB) 4S1B std
    u8*       C4T = (u8*)(Wp + 158 * MB);     // [158,196MB) 4S1B T
    uint32_t* KP  = (uint32_t*)(Wp + 196 * MB);  // 1.2MB
    uint32_t* VP  = (uint32_t*)(Wp + 198 * MB);  // 4.8MB -> ends 203MB

    const size_t planeC = (size_t)8 * 512 * 576;
    auto nblk = [](size_t n) { return (unsigned)((n + 255) / 256); };

    // ---- SepConv ----
    lif_f<<<nblk(planeC), 256, 0, stream>>>(x, nullptr, A, planeC, 1);
    transp<<<dim3(18, 16, 32), 256, 0, stream>>>(A, AT, 512);
    pw_tile<1><<<dim3(9, 32, 8), 256, 0, stream>>>(pw1_w, AT, pw1_s, pw1_b,
        nullptr, nullptr, B, nullptr, 1024, 512);
    dwlif<<<nblk((size_t)8 * 1024 * 576), 256, 0, stream>>>(B, dw_w, dw_s, dw_b, C4, 1024);
    transp<<<dim3(18, 32, 32), 256, 0, stream>>>(C4, BT, 1024);
    pw_tile<0><<<dim3(9, 16, 8), 256, 0, stream>>>(pw2_w, BT, pw2_s, pw2_b,
        nullptr, x, nullptr, X2, 512, 1024);

    // ---- Attention ----
    lif_f<<<nblk(planeC), 256, 0, stream>>>(X2, s_pos, A, planeC, (size_t)512 * 576);
    transp<<<dim3(18, 16, 32), 256, 0, stream>>>(A, AT, 512);
    pw_tile<1><<<dim3(9, 16, 8), 256, 0, stream>>>(k_w, AT, k_s, k_b,
        nullptr, nullptr, A, nullptr, 512, 512);
    bitpack<<<nblk((size_t)32 * 512 * 18), 256, 0, stream>>>(A, KP, (size_t)32 * 512 * 18);
    pw_tile<1><<<dim3(9, 64, 8), 256, 0, stream>>>(v_w, AT, v_s, v_b,
        nullptr, nullptr, C4, nullptr, 2048, 512);
    bitpack<<<nblk((size_t)32 * 2048 * 18), 256, 0, stream>>>(C4, VP, (size_t)32 * 2048 * 18);
    kvk_bit<<<dim3(8, 32), 256, 0, stream>>>(KP, VP, KV);
    pw_tile<1><<<dim3(9, 16, 8), 256, 0, stream>>>(q_w, AT, q_s, q_b,
        nullptr, nullptr, A, nullptr, 512, 512);
    transp<<<dim3(18, 16, 32), 256, 0, stream>>>(A, AT, 512);   // q_T (a_T dead)
    olifT<<<dim3(9, 2048, 8), 64, 0, stream>>>(AT, KV, C4);     // o_spk
    transp<<<dim3(18, 64, 32), 256, 0, stream>>>(C4, C4T, 2048);
    pw_tile<0><<<dim3(9, 16, 8), 256, 0, stream>>>(proj_w, C4T, proj_s, proj_b,
        nullptr, X2, nullptr, X2, 512, 2048);

    // ---- MLP ----
    lif_f<<<nblk(planeC), 256, 0, stream>>>(X2, nullptr, A, planeC, 1);
    transp<<<dim3(18, 16, 32), 256, 0, stream>>>(A, AT, 512);
    pw_tile<1><<<dim3(9, 64, 8), 256, 0, stream>>>(fc1_w, AT, fc1_s, fc1_b,
        fc1_c, nullptr, C4, nullptr, 2048, 512);
    transp<<<dim3(18, 64, 32), 256, 0, stream>>>(C4, C4T, 2048);
    pw_tile<0><<<dim3(9, 16, 8), 256, 0, stream>>>(fc2_w, C4T, fc2_s, fc2_b,
        fc2_c, X2, nullptr, out, 512, 2048);
}

// Round 28
// 4477.364 us; speedup vs baseline: 1.4278x; 1.4278x over previous
//
#include <hip/hip_runtime.h>
#include <cstdint>

#pragma clang fp contract(off)

typedef unsigned char u8;

// r23 = 3.40ms best. r27 showed weights (uniform broadcast) are cheap; the
// real cost is 8-way bank conflicts on spike ds_read_b128 (144B row stride).
// r28: XOR-swizzled spike tile [64][128] (chunk q -> q^(nl&7)), conflict-free
// reads, LDS 48KB -> 3 blocks/CU. BIT-EXACT: staging order only; fma order
// (ascending c within 256-chunks, seq folds) + epilogue/LIF unchanged.

__device__ __forceinline__ void lif_step(float& mem, float& spk, float v) {
    float m1 = __fmul_rn(mem, 0.25f);            // exact (pow2)
    float m2 = __fmul_rn(m1, (1.0f - spk));      // exact (x0 or x1)
    mem = __fadd_rn(m2, v);                      // one rounding
    spk = (mem > 0.5f) ? 1.0f : 0.0f;
}

__device__ __forceinline__ float ubf(uint32_t x, int j) {
    return (float)((x >> (j * 8)) & 0xffu);      // v_cvt_f32_ubyteN
}

// ---- LIF over T=4 from f32 source (+ optional pos broadcast) -> u8 ----
__global__ __launch_bounds__(256) void lif_f(const float* __restrict__ src,
                                             const float* __restrict__ pos,
                                             u8* __restrict__ dst,
                                             size_t plane, size_t cn) {
    size_t i = (size_t)blockIdx.x * 256 + threadIdx.x;
    if (i >= plane) return;
    float p = pos ? pos[i % cn] : 0.0f;
    float mem = 0.0f, spk = 0.0f;
#pragma unroll
    for (int t = 0; t < 4; ++t) {
        float v = src[(size_t)t * plane + i];
        if (pos) v = __fadd_rn(v, p);
        lif_step(mem, spk, v);
        dst[(size_t)t * plane + i] = (u8)spk;
    }
}

// ---- u8 transpose [g][R][576] -> [g][576][R], 32x32 LDS tiles ----
__global__ __launch_bounds__(256) void transp(const u8* __restrict__ in,
                                              u8* __restrict__ out, int R) {
    __shared__ u8 tile[32][33];
    int g = blockIdx.z;
    int r0 = blockIdx.y * 32;
    int n0 = blockIdx.x * 32;
    int tx = threadIdx.x & 31, ty = threadIdx.x >> 5;  // ty 0..7
    const u8* ip = in + ((size_t)g * R + r0) * 576 + n0;
#pragma unroll
    for (int k = 0; k < 4; ++k) {
        int r = ty + k * 8;
        tile[r][tx] = ip[(size_t)r * 576 + tx];
    }
    __syncthreads();
    u8* op = out + ((size_t)g * 576 + n0) * R + r0;
#pragma unroll
    for (int k = 0; k < 4; ++k) {
        int r = ty + k * 8;
        op[(size_t)r * R + tx] = tile[tx][r];
    }
}

// ===========================================================================
// Tiled 1x1-conv: block = 64n x 32o, b fixed. XOR-swizzled spike LDS tile
// (conflict-free reads); weight tile broadcast from LDS (uniform address).
// p[8][4] in-chunk accs (ascending c), a[8][4] folded at 256-c boundaries.
// DO_LIF=1: BN+LIF -> u8 dst.  DO_LIF=0: BN+residual -> f32 outp.
// ===========================================================================
template <int DO_LIF>
__global__ __launch_bounds__(256) void pw_tile(
    const float* __restrict__ W, const u8* __restrict__ ST,
    const float* __restrict__ sc, const float* __restrict__ bi,
    const float* __restrict__ cb, const float* __restrict__ res,
    u8* __restrict__ dst, float* __restrict__ outp, int O, int C) {
    __shared__ u8 spk[4][64][128];
    __shared__ float wt[32][128];
    int lane = threadIdx.x & 63;
    int wave = threadIdx.x >> 6;
    int n0 = blockIdx.x * 64;
    int o0 = blockIdx.y * 32;
    int b = blockIdx.z;
    int n = n0 + lane;
    int wo = wave * 8;
    int lsw = lane & 7;                      // read-side chunk XOR
    float a[8][4] = {}, p[8][4] = {};
    for (int c0 = 0; c0 < C; c0 += 256) {
        for (int s = 0; s < 2; ++s) {
            int cs = c0 + s * 128;
            __syncthreads();
            {   // stage spikes swizzled: chunk q -> q ^ (nl&7)
                int t = threadIdx.x >> 6, nl = threadIdx.x & 63;
                const uint4* g4 = (const uint4*)(ST +
                    ((size_t)(t * 8 + b) * 576 + n0 + nl) * C + cs);
                uint4* l4 = (uint4*)&spk[t][nl][0];
                int sw = nl & 7;
#pragma unroll
                for (int q = 0; q < 8; ++q) l4[q ^ sw] = g4[q];
            }
            {   // stage weights: 32 rows x 128 f32
                int row = threadIdx.x >> 3, seg = (threadIdx.x & 7) * 16;
                const float4* gw = (const float4*)(W +
                    (size_t)(o0 + row) * C + cs + seg);
                float4* lw = (float4*)&wt[row][seg];
#pragma unroll
                for (int q = 0; q < 4; ++q) lw[q] = gw[q];
            }
            __syncthreads();
#pragma unroll
            for (int cq16 = 0; cq16 < 8; ++cq16) {
                int pc = (cq16 ^ lsw) << 4;          // swizzled byte offset
                uint4 s0 = *(const uint4*)&spk[0][lane][pc];
                uint4 s1 = *(const uint4*)&spk[1][lane][pc];
                uint4 s2 = *(const uint4*)&spk[2][lane][pc];
                uint4 s3 = *(const uint4*)&spk[3][lane][pc];
                int cq = cq16 << 4;
#pragma unroll
                for (int d = 0; d < 4; ++d) {
                    float4 wk[8];
#pragma unroll
                    for (int k = 0; k < 8; ++k)
                        wk[k] = *(const float4*)&wt[wo + k][cq + d * 4];
                    uint32_t u0 = (&s0.x)[d], u1 = (&s1.x)[d];
                    uint32_t u2 = (&s2.x)[d], u3 = (&s3.x)[d];
#pragma unroll
                    for (int j = 0; j < 4; ++j) {
                        float f0 = ubf(u0, j), f1 = ubf(u1, j);
                        float f2 = ubf(u2, j), f3 = ubf(u3, j);
#pragma unroll
                        for (int k = 0; k < 8; ++k) {
                            float w = (&wk[k].x)[j];
                            p[k][0] = __fmaf_rn(f0, w, p[k][0]);
                            p[k][1] = __fmaf_rn(f1, w, p[k][1]);
                            p[k][2] = __fmaf_rn(f2, w, p[k][2]);
                            p[k][3] = __fmaf_rn(f3, w, p[k][3]);
                        }
                    }
                }
            }
        }
#pragma unroll
        for (int k = 0; k < 8; ++k)
#pragma unroll
            for (int t = 0; t < 4; ++t) {
                a[k][t] = __fadd_rn(a[k][t], p[k][t]);
                p[k][t] = 0.0f;
            }
    }
    size_t planeO = (size_t)8 * O * 576;
#pragma unroll
    for (int k = 0; k < 8; ++k) {
        int o = o0 + wo + k;
        float s_ = sc[o], b_ = bi[o];
        if (DO_LIF) {
            float mem = 0.f, spkr = 0.f;
#pragma unroll
            for (int t = 0; t < 4; ++t) {
                float acc = a[k][t];
                if (cb) acc = __fadd_rn(acc, cb[o]);
                float v = __fadd_rn(__fmul_rn(acc, s_), b_);
                lif_step(mem, spkr, v);
                dst[(size_t)t * planeO + ((size_t)b * O + o) * 576 + n] = (u8)spkr;
            }
        } else {
#pragma unroll
            for (int t = 0; t < 4; ++t) {
                float acc = a[k][t];
                if (cb) acc = __fadd_rn(acc, cb[o]);
                float v = __fadd_rn(__fmul_rn(acc, s_), b_);
                size_t idx = (size_t)t * planeO + ((size_t)b * O + o) * 576 + n;
                outp[idx] = __fadd_rn(res[idx], v);
            }
        }
    }
}

// ---- fused depthwise 3x3 (cross-correlation, SAME, zero-pad) + BN + LIF ----
__global__ __launch_bounds__(256) void dwlif(
    const u8* __restrict__ in, const float* __restrict__ w9,
    const float* __restrict__ sc, const float* __restrict__ bi,
    u8* __restrict__ dst, int Ch) {
    size_t i = (size_t)blockIdx.x * 256 + threadIdx.x;
    size_t total = (size_t)8 * Ch * 576;
    if (i >= total) return;
    int n = (int)(i % 576);
    int c = (int)((i / 576) % Ch);
    int b = (int)(i / ((size_t)Ch * 576));
    int h = n / 24, w = n % 24;
    const float* wc = w9 + (size_t)c * 9;
    float s_ = sc[c], b_ = bi[c];
    float mem = 0.0f, spk = 0.0f;
#pragma unroll
    for (int t = 0; t < 4; ++t) {
        const u8* base = in + ((size_t)(t * 8 + b) * Ch + c) * 576;
        float acc = 0.0f;
#pragma unroll
        for (int ii = 0; ii < 3; ++ii) {
            int hh = h + ii - 1;
            if (hh < 0 || hh >= 24) continue;
#pragma unroll
            for (int jj = 0; jj < 3; ++jj) {
                int ww = w + jj - 1;
                if (ww < 0 || ww >= 24) continue;
                if (base[hh * 24 + ww]) acc = __fadd_rn(acc, wc[ii * 3 + jj]);
            }
        }
        float v = __fadd_rn(__fmul_rn(acc, s_), b_);
        lif_step(mem, spk, v);
        dst[((size_t)(t * 8 + b) * Ch + c) * 576 + n] = (u8)spk;
    }
}

// ---- bitpack spikes along n: [rows][576] u8 -> [rows][18] u32 ----
__global__ __launch_bounds__(256) void bitpack(const u8* __restrict__ in,
                                               uint32_t* __restrict__ out,
                                               size_t nwords) {
    size_t i = (size_t)blockIdx.x * 256 + threadIdx.x;
    if (i >= nwords) return;
    size_t r = i / 18; int w = (int)(i % 18);
    const u8* p = in + r * 576 + (size_t)w * 32;
    uint32_t m = 0;
#pragma unroll
    for (int j = 0; j < 32; ++j) m |= (p[j] ? 1u : 0u) << j;
    out[i] = m;
}

// ---- kv via AND+popcount (exact integer, order-free) ----
__global__ __launch_bounds__(256) void kvk_bit(const uint32_t* __restrict__ KP,
                                               const uint32_t* __restrict__ VP,
                                               float* __restrict__ KV) {
    int e = threadIdx.x;       // 0..255
    int h = blockIdx.x;        // 0..7
    int g = blockIdx.y;        // 0..31
    uint32_t v[18];
    const uint32_t* vp = VP + ((size_t)g * 2048 + h * 256 + e) * 18;
#pragma unroll
    for (int w = 0; w < 18; ++w) v[w] = vp[w];
    __shared__ uint32_t ks[64][18];
    const uint32_t* kp = KP + ((size_t)g * 512 + h * 64) * 18;
    for (int idx = threadIdx.x; idx < 64 * 18; idx += 256)
        ks[idx / 18][idx % 18] = kp[idx];
    __syncthreads();
    float* kvo = KV + ((size_t)(g * 8 + h)) * (64 * 256);
    for (int d = 0; d < 64; ++d) {
        int s = 0;
#pragma unroll
        for (int w = 0; w < 18; ++w) s += __popc(ks[d][w] & v[w]);
        kvo[d * 256 + e] = (float)s;  // exact int
    }
}

// ---- o = 0.25 * q.kv (exact ints) + LIF -> u8 std; q transposed ----
__global__ __launch_bounds__(64) void olifT(const u8* __restrict__ QT,
                                            const float* __restrict__ KV,
                                            u8* __restrict__ dst) {
    int n = blockIdx.x * 64 + threadIdx.x;
    int ef = blockIdx.y;
    int b = blockIdx.z;
    int h = ef >> 8, e = ef & 255;
    float mem = 0.f, spk = 0.f;
#pragma unroll
    for (int t = 0; t < 4; ++t) {
        int g = t * 8 + b;
        const u8* q = QT + ((size_t)g * 576 + n) * 512 + h * 64;
        const float* kvg = KV + ((size_t)(g * 8 + h)) * (64 * 256) + e;
        float acc = 0.f;
#pragma unroll
        for (int dq = 0; dq < 64; dq += 16) {
            uint4 qw = *(const uint4*)(q + dq);
#pragma unroll
            for (int d = 0; d < 4; ++d) {
                uint32_t u = (&qw.x)[d];
#pragma unroll
                for (int j = 0; j < 4; ++j)
                    acc = __fmaf_rn(ubf(u, j), kvg[(size_t)(dq + d * 4 + j) * 256], acc);
            }
        }
        float v = __fmul_rn(0.25f, acc);  // exact
        lif_step(mem, spk, v);
        dst[((size_t)g * 2048 + ef) * 576 + n] = (u8)spk;
    }
}

// ---------------------------------------------------------------------------
extern "C" void kernel_launch(void* const* d_in, const int* in_sizes, int n_in,
                              void* d_out, int out_size, void* d_ws, size_t ws_size,
                              hipStream_t stream) {
    const float* x        = (const float*)d_in[0];
    const float* pw1_w    = (const float*)d_in[1];
    const float* pw1_s    = (const float*)d_in[2];
    const float* pw1_b    = (const float*)d_in[3];
    const float* dw_w     = (const float*)d_in[4];
    const float* dw_s     = (const float*)d_in[5];
    const float* dw_b     = (const float*)d_in[6];
    const float* pw2_w    = (const float*)d_in[7];
    const float* pw2_s    = (const float*)d_in[8];
    const float* pw2_b    = (const float*)d_in[9];
    const float* s_pos    = (const float*)d_in[10];
    const float* q_w      = (const float*)d_in[11];
    const float* q_s      = (const float*)d_in[12];
    const float* q_b      = (const float*)d_in[13];
    const float* k_w      = (const float*)d_in[14];
    const float* k_s      = (const float*)d_in[15];
    const float* k_b      = (const float*)d_in[16];
    const float* v_w      = (const float*)d_in[17];
    const float* v_s      = (const float*)d_in[18];
    const float* v_b      = (const float*)d_in[19];
    const float* proj_w   = (const float*)d_in[20];
    const float* proj_s   = (const float*)d_in[21];
    const float* proj_b   = (const float*)d_in[22];
    const float* fc1_w    = (const float*)d_in[23];
    const float* fc1_c    = (const float*)d_in[24];
    const float* fc1_s    = (const float*)d_in[25];
    const float* fc1_b    = (const float*)d_in[26];
    const float* fc2_w    = (const float*)d_in[27];
    const float* fc2_c    = (const float*)d_in[28];
    const float* fc2_s    = (const float*)d_in[29];
    const float* fc2_b    = (const float*)d_in[30];
    float* out = (float*)d_out;
    (void)ws_size; (void)n_in; (void)in_sizes; (void)out_size;

    const size_t MB = 1024 * 1024;
    char* Wp = (char*)d_ws;
    float*    X2  = (float*)(Wp);             // [0,40MB)    x2 -> x3 f32
    float*    KV  = (float*)(Wp + 40 * MB);   // [40,60MB)
    u8*       A   = (u8*)(Wp + 60 * MB);      // [60,70MB)   S1B std
    u8*       AT  = (u8*)(Wp + 70 * MB);      // [70,80MB)   S1B transposed
    u8*       B   = (u8*)(Wp + 80 * MB);      // [80,100MB)  2S1B std (y1)
    u8*       BT  = (u8*)(Wp + 100 * MB);     // [100,120MB) 2S1B T (y2_T)
    u8*       C4  = (u8*)(Wp + 120 * MB);     // [120,158MB) 4S1B std
    u8*       C4T = (u8*)(Wp + 158 * MB);     // [158,196MB) 4S1B T
    uint32_t* KP  = (uint32_t*)(Wp + 196 * MB);  // 1.2MB
    uint32_t* VP  = (uint32_t*)(Wp + 198 * MB);  // 4.8MB -> ends 203MB

    const size_t planeC = (size_t)8 * 512 * 576;
    auto nblk = [](size_t n) { return (unsigned)((n + 255) / 256); };

    // ---- SepConv ----
    lif_f<<<nblk(planeC), 256, 0, stream>>>(x, nullptr, A, planeC, 1);
    transp<<<dim3(18, 16, 32), 256, 0, stream>>>(A, AT, 512);
    pw_tile<1><<<dim3(9, 32, 8), 256, 0, stream>>>(pw1_w, AT, pw1_s, pw1_b,
        nullptr, nullptr, B, nullptr, 1024, 512);
    dwlif<<<nblk((size_t)8 * 1024 * 576), 256, 0, stream>>>(B, dw_w, dw_s, dw_b, C4, 1024);
    transp<<<dim3(18, 32, 32), 256, 0, stream>>>(C4, BT, 1024);
    pw_tile<0><<<dim3(9, 16, 8), 256, 0, stream>>>(pw2_w, BT, pw2_s, pw2_b,
        nullptr, x, nullptr, X2, 512, 1024);

    // ---- Attention ----
    lif_f<<<nblk(planeC), 256, 0, stream>>>(X2, s_pos, A, planeC, (size_t)512 * 576);
    transp<<<dim3(18, 16, 32), 256, 0, stream>>>(A, AT, 512);
    pw_tile<1><<<dim3(9, 16, 8), 256, 0, stream>>>(k_w, AT, k_s, k_b,
        nullptr, nullptr, A, nullptr, 512, 512);
    bitpack<<<nblk((size_t)32 * 512 * 18), 256, 0, stream>>>(A, KP, (size_t)32 * 512 * 18);
    pw_tile<1><<<dim3(9, 64, 8), 256, 0, stream>>>(v_w, AT, v_s, v_b,
        nullptr, nullptr, C4, nullptr, 2048, 512);
    bitpack<<<nblk((size_t)32 * 2048 * 18), 256, 0, stream>>>(C4, VP, (size_t)32 * 2048 * 18);
    kvk_bit<<<dim3(8, 32), 256, 0, stream>>>(KP, VP, KV);
    pw_tile<1><<<dim3(9, 16, 8), 256, 0, stream>>>(q_w, AT, q_s, q_b,
        nullptr, nullptr, A, nullptr, 512, 512);
    transp<<<dim3(18, 16, 32), 256, 0, stream>>>(A, AT, 512);   // q_T (a_T dead)
    olifT<<<dim3(9, 2048, 8), 64, 0, stream>>>(AT, KV, C4);     // o_spk
    transp<<<dim3(18, 64, 32), 256, 0, stream>>>(C4, C4T, 2048);
    pw_tile<0><<<dim3(9, 16, 8), 256, 0, stream>>>(proj_w, C4T, proj_s, proj_b,
        nullptr, X2, nullptr, X2, 512, 2048);

    // ---- MLP ----
    lif_f<<<nblk(planeC), 256, 0, stream>>>(X2, nullptr, A, planeC, 1);
    transp<<<dim3(18, 16, 32), 256, 0, stream>>>(A, AT, 512);
    pw_tile<1><<<dim3(9, 64, 8), 256, 0, stream>>>(fc1_w, AT, fc1_s, fc1_b,
        fc1_c, nullptr, C4, nullptr, 2048, 512);
    transp<<<dim3(18, 64, 32), 256, 0, stream>>>(C4, C4T, 2048);
    pw_tile<0><<<dim3(9, 16, 8), 256, 0, stream>>>(fc2_w, C4T, fc2_s, fc2_b,
        fc2_c, X2, nullptr, out, 512, 2048);
}

// Round 29
// 3383.996 us; speedup vs baseline: 1.8891x; 1.3231x over previous
//
#include <hip/hip_runtime.h>
#include <cstdint>

#pragma clang fp contract(off)

typedef unsigned char u8;

// r23 = 3.40ms champion (LDS 53.76KB -> only 2 blocks/CU; VALUBusy 65%).
// r29 = r23 with wt pad removed ([32][132] -> [32][128]; weight reads are
// wave-uniform broadcasts, pad was useless): LDS 53,248B -> 3 blocks/CU.
// BIT-EXACT: per (o,t,n) acc = seq-ascending-c fma within each 256-chunk,
// chunk sums folded sequentially; epilogue (cb,*s,+b) + LIF chain as r20.

__device__ __forceinline__ void lif_step(float& mem, float& spk, float v) {
    float m1 = __fmul_rn(mem, 0.25f);            // exact (pow2)
    float m2 = __fmul_rn(m1, (1.0f - spk));      // exact (x0 or x1)
    mem = __fadd_rn(m2, v);                      // one rounding
    spk = (mem > 0.5f) ? 1.0f : 0.0f;
}

__device__ __forceinline__ float ubf(uint32_t x, int j) {
    return (float)((x >> (j * 8)) & 0xffu);      // v_cvt_f32_ubyteN
}

// ---- LIF over T=4 from f32 source (+ optional pos broadcast) -> u8 ----
__global__ __launch_bounds__(256) void lif_f(const float* __restrict__ src,
                                             const float* __restrict__ pos,
                                             u8* __restrict__ dst,
                                             size_t plane, size_t cn) {
    size_t i = (size_t)blockIdx.x * 256 + threadIdx.x;
    if (i >= plane) return;
    float p = pos ? pos[i % cn] : 0.0f;
    float mem = 0.0f, spk = 0.0f;
#pragma unroll
    for (int t = 0; t < 4; ++t) {
        float v = src[(size_t)t * plane + i];
        if (pos) v = __fadd_rn(v, p);
        lif_step(mem, spk, v);
        dst[(size_t)t * plane + i] = (u8)spk;
    }
}

// ---- u8 transpose [g][R][576] -> [g][576][R], 32x32 LDS tiles ----
__global__ __launch_bounds__(256) void transp(const u8* __restrict__ in,
                                              u8* __restrict__ out, int R) {
    __shared__ u8 tile[32][33];
    int g = blockIdx.z;
    int r0 = blockIdx.y * 32;
    int n0 = blockIdx.x * 32;
    int tx = threadIdx.x & 31, ty = threadIdx.x >> 5;  // ty 0..7
    const u8* ip = in + ((size_t)g * R + r0) * 576 + n0;
#pragma unroll
    for (int k = 0; k < 4; ++k) {
        int r = ty + k * 8;
        tile[r][tx] = ip[(size_t)r * 576 + tx];
    }
    __syncthreads();
    u8* op = out + ((size_t)g * 576 + n0) * R + r0;
#pragma unroll
    for (int k = 0; k < 4; ++k) {
        int r = ty + k * 8;
        op[(size_t)r * R + tx] = tile[tx][r];
    }
}

// ===========================================================================
// Tiled 1x1-conv: block = 64n x 32o, b fixed. LDS-staged 128-c slices.
// p[8][4] in-chunk accs (ascending c), a[8][4] folded at 256-c boundaries.
// DO_LIF=1: BN+LIF -> u8 dst.  DO_LIF=0: BN+residual -> f32 outp.
// ===========================================================================
template <int DO_LIF>
__global__ __launch_bounds__(256) void pw_tile(
    const float* __restrict__ W, const u8* __restrict__ ST,
    const float* __restrict__ sc, const float* __restrict__ bi,
    const float* __restrict__ cb, const float* __restrict__ res,
    u8* __restrict__ dst, float* __restrict__ outp, int O, int C) {
    __shared__ u8 spk[4][64][144];
    __shared__ float wt[32][128];
    int lane = threadIdx.x & 63;
    int wave = threadIdx.x >> 6;
    int n0 = blockIdx.x * 64;
    int o0 = blockIdx.y * 32;
    int b = blockIdx.z;
    int n = n0 + lane;
    int wo = wave * 8;
    float a[8][4] = {}, p[8][4] = {};
    for (int c0 = 0; c0 < C; c0 += 256) {
        for (int s = 0; s < 2; ++s) {
            int cs = c0 + s * 128;
            __syncthreads();
            {   // stage spikes: 256 rows (4t x 64n), 128B each
                int t = threadIdx.x >> 6, nl = threadIdx.x & 63;
                const uint4* g4 = (const uint4*)(ST +
                    ((size_t)(t * 8 + b) * 576 + n0 + nl) * C + cs);
                uint4* l4 = (uint4*)&spk[t][nl][0];
#pragma unroll
                for (int q = 0; q < 8; ++q) l4[q] = g4[q];
            }
            {   // stage weights: 32 rows x 128 f32
                int row = threadIdx.x >> 3, seg = (threadIdx.x & 7) * 16;
                const float4* gw = (const float4*)(W +
                    (size_t)(o0 + row) * C + cs + seg);
                float4* lw = (float4*)&wt[row][seg];
#pragma unroll
                for (int q = 0; q < 4; ++q) lw[q] = gw[q];
            }
            __syncthreads();
            for (int cq = 0; cq < 128; cq += 16) {
                uint4 s0 = *(const uint4*)&spk[0][lane][cq];
                uint4 s1 = *(const uint4*)&spk[1][lane][cq];
                uint4 s2 = *(const uint4*)&spk[2][lane][cq];
                uint4 s3 = *(const uint4*)&spk[3][lane][cq];
#pragma unroll
                for (int d = 0; d < 4; ++d) {
                    float4 wk[8];
#pragma unroll
                    for (int k = 0; k < 8; ++k)
                        wk[k] = *(const float4*)&wt[wo + k][cq + d * 4];
                    uint32_t u0 = (&s0.x)[d], u1 = (&s1.x)[d];
                    uint32_t u2 = (&s2.x)[d], u3 = (&s3.x)[d];
#pragma unroll
                    for (int j = 0; j < 4; ++j) {
                        float f0 = ubf(u0, j), f1 = ubf(u1, j);
                        float f2 = ubf(u2, j), f3 = ubf(u3, j);
#pragma unroll
                        for (int k = 0; k < 8; ++k) {
                            float w = (&wk[k].x)[j];
                            p[k][0] = __fmaf_rn(f0, w, p[k][0]);
                            p[k][1] = __fmaf_rn(f1, w, p[k][1]);
                            p[k][2] = __fmaf_rn(f2, w, p[k][2]);
                            p[k][3] = __fmaf_rn(f3, w, p[k][3]);
                        }
                    }
                }
            }
        }
#pragma unroll
        for (int k = 0; k < 8; ++k)
#pragma unroll
            for (int t = 0; t < 4; ++t) {
                a[k][t] = __fadd_rn(a[k][t], p[k][t]);
                p[k][t] = 0.0f;
            }
    }
    size_t planeO = (size_t)8 * O * 576;
#pragma unroll
    for (int k = 0; k < 8; ++k) {
        int o = o0 + wo + k;
        float s_ = sc[o], b_ = bi[o];
        if (DO_LIF) {
            float mem = 0.f, spkr = 0.f;
#pragma unroll
            for (int t = 0; t < 4; ++t) {
                float acc = a[k][t];
                if (cb) acc = __fadd_rn(acc, cb[o]);
                float v = __fadd_rn(__fmul_rn(acc, s_), b_);
                lif_step(mem, spkr, v);
                dst[(size_t)t * planeO + ((size_t)b * O + o) * 576 + n] = (u8)spkr;
            }
        } else {
#pragma unroll
            for (int t = 0; t < 4; ++t) {
                float acc = a[k][t];
                if (cb) acc = __fadd_rn(acc, cb[o]);
                float v = __fadd_rn(__fmul_rn(acc, s_), b_);
                size_t idx = (size_t)t * planeO + ((size_t)b * O + o) * 576 + n;
                outp[idx] = __fadd_rn(res[idx], v);
            }
        }
    }
}

// ---- fused depthwise 3x3 (cross-correlation, SAME, zero-pad) + BN + LIF ----
__global__ __launch_bounds__(256) void dwlif(
    const u8* __restrict__ in, const float* __restrict__ w9,
    const float* __restrict__ sc, const float* __restrict__ bi,
    u8* __restrict__ dst, int Ch) {
    size_t i = (size_t)blockIdx.x * 256 + threadIdx.x;
    size_t total = (size_t)8 * Ch * 576;
    if (i >= total) return;
    int n = (int)(i % 576);
    int c = (int)((i / 576) % Ch);
    int b = (int)(i / ((size_t)Ch * 576));
    int h = n / 24, w = n % 24;
    const float* wc = w9 + (size_t)c * 9;
    float s_ = sc[c], b_ = bi[c];
    float mem = 0.0f, spk = 0.0f;
#pragma unroll
    for (int t = 0; t < 4; ++t) {
        const u8* base = in + ((size_t)(t * 8 + b) * Ch + c) * 576;
        float acc = 0.0f;
#pragma unroll
        for (int ii = 0; ii < 3; ++ii) {
            int hh = h + ii - 1;
            if (hh < 0 || hh >= 24) continue;
#pragma unroll
            for (int jj = 0; jj < 3; ++jj) {
                int ww = w + jj - 1;
                if (ww < 0 || ww >= 24) continue;
                if (base[hh * 24 + ww]) acc = __fadd_rn(acc, wc[ii * 3 + jj]);
            }
        }
        float v = __fadd_rn(__fmul_rn(acc, s_), b_);
        lif_step(mem, spk, v);
        dst[((size_t)(t * 8 + b) * Ch + c) * 576 + n] = (u8)spk;
    }
}

// ---- bitpack spikes along n: [rows][576] u8 -> [rows][18] u32 ----
__global__ __launch_bounds__(256) void bitpack(const u8* __restrict__ in,
                                               uint32_t* __restrict__ out,
                                               size_t nwords) {
    size_t i = (size_t)blockIdx.x * 256 + threadIdx.x;
    if (i >= nwords) return;
    size_t r = i / 18; int w = (int)(i % 18);
    const u8* p = in + r * 576 + (size_t)w * 32;
    uint32_t m = 0;
#pragma unroll
    for (int j = 0; j < 32; ++j) m |= (p[j] ? 1u : 0u) << j;
    out[i] = m;
}

// ---- kv via AND+popcount (exact integer, order-free) ----
__global__ __launch_bounds__(256) void kvk_bit(const uint32_t* __restrict__ KP,
                                               const uint32_t* __restrict__ VP,
                                               float* __restrict__ KV) {
    int e = threadIdx.x;       // 0..255
    int h = blockIdx.x;        // 0..7
    int g = blockIdx.y;        // 0..31
    uint32_t v[18];
    const uint32_t* vp = VP + ((size_t)g * 2048 + h * 256 + e) * 18;
#pragma unroll
    for (int w = 0; w < 18; ++w) v[w] = vp[w];
    __shared__ uint32_t ks[64][18];
    const uint32_t* kp = KP + ((size_t)g * 512 + h * 64) * 18;
    for (int idx = threadIdx.x; idx < 64 * 18; idx += 256)
        ks[idx / 18][idx % 18] = kp[idx];
    __syncthreads();
    float* kvo = KV + ((size_t)(g * 8 + h)) * (64 * 256);
    for (int d = 0; d < 64; ++d) {
        int s = 0;
#pragma unroll
        for (int w = 0; w < 18; ++w) s += __popc(ks[d][w] & v[w]);
        kvo[d * 256 + e] = (float)s;  // exact int
    }
}

// ---- o = 0.25 * q.kv (exact ints) + LIF -> u8 std; q transposed ----
__global__ __launch_bounds__(64) void olifT(const u8* __restrict__ QT,
                                            const float* __restrict__ KV,
                                            u8* __restrict__ dst) {
    int n = blockIdx.x * 64 + threadIdx.x;
    int ef = blockIdx.y;
    int b = blockIdx.z;
    int h = ef >> 8, e = ef & 255;
    float mem = 0.f, spk = 0.f;
#pragma unroll
    for (int t = 0; t < 4; ++t) {
        int g = t * 8 + b;
        const u8* q = QT + ((size_t)g * 576 + n) * 512 + h * 64;
        const float* kvg = KV + ((size_t)(g * 8 + h)) * (64 * 256) + e;
        float acc = 0.f;
#pragma unroll
        for (int dq = 0; dq < 64; dq += 16) {
            uint4 qw = *(const uint4*)(q + dq);
#pragma unroll
            for (int d = 0; d < 4; ++d) {
                uint32_t u = (&qw.x)[d];
#pragma unroll
                for (int j = 0; j < 4; ++j)
                    acc = __fmaf_rn(ubf(u, j), kvg[(size_t)(dq + d * 4 + j) * 256], acc);
            }
        }
        float v = __fmul_rn(0.25f, acc);  // exact
        lif_step(mem, spk, v);
        dst[((size_t)g * 2048 + ef) * 576 + n] = (u8)spk;
    }
}

// ---------------------------------------------------------------------------
extern "C" void kernel_launch(void* const* d_in, const int* in_sizes, int n_in,
                              void* d_out, int out_size, void* d_ws, size_t ws_size,
                              hipStream_t stream) {
    const float* x        = (const float*)d_in[0];
    const float* pw1_w    = (const float*)d_in[1];
    const float* pw1_s    = (const float*)d_in[2];
    const float* pw1_b    = (const float*)d_in[3];
    const float* dw_w     = (const float*)d_in[4];
    const float* dw_s     = (const float*)d_in[5];
    const float* dw_b     = (const float*)d_in[6];
    const float* pw2_w    = (const float*)d_in[7];
    const float* pw2_s    = (const float*)d_in[8];
    const float* pw2_b    = (const float*)d_in[9];
    const float* s_pos    = (const float*)d_in[10];
    const float* q_w      = (const float*)d_in[11];
    const float* q_s      = (const float*)d_in[12];
    const float* q_b      = (const float*)d_in[13];
    const float* k_w      = (const float*)d_in[14];
    const float* k_s      = (const float*)d_in[15];
    const float* k_b      = (const float*)d_in[16];
    const float* v_w      = (const float*)d_in[17];
    const float* v_s      = (const float*)d_in[18];
    const float* v_b      = (const float*)d_in[19];
    const float* proj_w   = (const float*)d_in[20];
    const float* proj_s   = (const float*)d_in[21];
    const float* proj_b   = (const float*)d_in[22];
    const float* fc1_w    = (const float*)d_in[23];
    const float* fc1_c    = (const float*)d_in[24];
    const float* fc1_s    = (const float*)d_in[25];
    const float* fc1_b    = (const float*)d_in[26];
    const float* fc2_w    = (const float*)d_in[27];
    const float* fc2_c    = (const float*)d_in[28];
    const float* fc2_s    = (const float*)d_in[29];
    const float* fc2_b    = (const float*)d_in[30];
    float* out = (float*)d_out;
    (void)ws_size; (void)n_in; (void)in_sizes; (void)out_size;

    const size_t MB = 1024 * 1024;
    char* Wp = (char*)d_ws;
    float*    X2  = (float*)(Wp);             // [0,40MB)    x2 -> x3 f32
    float*    KV  = (float*)(Wp + 40 * MB);   // [40,60MB)
    u8*       A   = (u8*)(Wp + 60 * MB);      // [60,70MB)   S1B std
    u8*       AT  = (u8*)(Wp + 70 * MB);      // [70,80MB)   S1B transposed
    u8*       B   = (u8*)(Wp + 80 * MB);      // [80,100MB)  2S1B std (y1)
    u8*       BT  = (u8*)(Wp + 100 * MB);     // [100,120MB) 2S1B T (y2_T)
    u8*       C4  = (u8*)(Wp + 120 * MB);     // [120,158MB) 4S1B std
    u8*       C4T = (u8*)(Wp + 158 * MB);     // [158,196MB) 4S1B T
    uint32_t* KP  = (uint32_t*)(Wp + 196 * MB);  // 1.2MB
    uint32_t* VP  = (uint32_t*)(Wp + 198 * MB);  // 4.8MB -> ends 203MB

    const size_t planeC = (size_t)8 * 512 * 576;
    auto nblk = [](size_t n) { return (unsigned)((n + 255) / 256); };

    // ---- SepConv ----
    lif_f<<<nblk(planeC), 256, 0, stream>>>(x, nullptr, A, planeC, 1);
    transp<<<dim3(18, 16, 32), 256, 0, stream>>>(A, AT, 512);
    pw_tile<1><<<dim3(9, 32, 8), 256, 0, stream>>>(pw1_w, AT, pw1_s, pw1_b,
        nullptr, nullptr, B, nullptr, 1024, 512);
    dwlif<<<nblk((size_t)8 * 1024 * 576), 256, 0, stream>>>(B, dw_w, dw_s, dw_b, C4, 1024);
    transp<<<dim3(18, 32, 32), 256, 0, stream>>>(C4, BT, 1024);
    pw_tile<0><<<dim3(9, 16, 8), 256, 0, stream>>>(pw2_w, BT, pw2_s, pw2_b,
        nullptr, x, nullptr, X2, 512, 1024);

    // ---- Attention ----
    lif_f<<<nblk(planeC), 256, 0, stream>>>(X2, s_pos, A, planeC, (size_t)512 * 576);
    transp<<<dim3(18, 16, 32), 256, 0, stream>>>(A, AT, 512);
    pw_tile<1><<<dim3(9, 16, 8), 256, 0, stream>>>(k_w, AT, k_s, k_b,
        nullptr, nullptr, A, nullptr, 512, 512);
    bitpack<<<nblk((size_t)32 * 512 * 18), 256, 0, stream>>>(A, KP, (size_t)32 * 512 * 18);
    pw_tile<1><<<dim3(9, 64, 8), 256, 0, stream>>>(v_w, AT, v_s, v_b,
        nullptr, nullptr, C4, nullptr, 2048, 512);
    bitpack<<<nblk((size_t)32 * 2048 * 18), 256, 0, stream>>>(C4, VP, (size_t)32 * 2048 * 18);
    kvk_bit<<<dim3(8, 32), 256, 0, stream>>>(KP, VP, KV);
    pw_tile<1><<<dim3(9, 16, 8), 256, 0, stream>>>(q_w, AT, q_s, q_b,
        nullptr, nullptr, A, nullptr, 512, 512);
    transp<<<dim3(18, 16, 32), 256, 0, stream>>>(A, AT, 512);   // q_T (a_T dead)
    olifT<<<dim3(9, 2048, 8), 64, 0, stream>>>(AT, KV, C4);     // o_spk
    transp<<<dim3(18, 64, 32), 256, 0, stream>>>(C4, C4T, 2048);
    pw_tile<0><<<dim3(9, 16, 8), 256, 0, stream>>>(proj_w, C4T, proj_s, proj_b,
        nullptr, X2, nullptr, X2, 512, 2048);

    // ---- MLP ----
    lif_f<<<nblk(planeC), 256, 0, stream>>>(X2, nullptr, A, planeC, 1);
    transp<<<dim3(18, 16, 32), 256, 0, stream>>>(A, AT, 512);
    pw_tile<1><<<dim3(9, 64, 8), 256, 0, stream>>>(fc1_w, AT, fc1_s, fc1_b,
        fc1_c, nullptr, C4, nullptr, 2048, 512);
    transp<<<dim3(18, 64, 32), 256, 0, stream>>>(C4, C4T, 2048);
    pw_tile<0><<<dim3(9, 16, 8), 256, 0, stream>>>(fc2_w, C4T, fc2_s, fc2_b,
        fc2_c, X2, nullptr, out, 512, 2048);
}